// Round 1
// baseline (101.401 us; speedup 1.0000x reference)
//
#include <hip/hip_runtime.h>

#define NI 2048   // num_in_caps
#define NJ 64     // num_caps
#define NC 32     // caps_dim
#define NB 32     // batch
#define ND 16     // in_caps_dim

// ---------------- init: zero the accumulator ----------------
__global__ void caps_init(float* __restrict__ ws) {
    int i = blockIdx.x * 256 + threadIdx.x;   // grid 256 * 256 = 65536
    ws[i] = 0.0f;
}

// ---------------- main: s_acc[b,j,c] += sum_{i,d} x*W ----------------
// grid = 1024 blocks (64 j * 16 i-chunks of 128), block = 256 (4 waves)
// lane: q = lane&3 (d-quad), cb = (lane>>2)&7 (c in {cb,cb+8,cb+16,cb+24}), ip = lane>>5 (i parity)
// wave handles i-pair {ibase + ch*8 + wave*2 + ip}
__global__ __launch_bounds__(256, 2)
void caps_main(const float* __restrict__ x, const float* __restrict__ W,
               float* __restrict__ ws)
{
    const int tid  = threadIdx.x;
    const int wave = tid >> 6;
    const int lane = tid & 63;
    const int q    = lane & 3;
    const int cb   = (lane >> 2) & 7;
    const int ip   = lane >> 5;

    const int j      = blockIdx.x >> 4;
    const int ichunk = blockIdx.x & 15;
    const int ibase0 = ichunk * 128;

    // [buf][b][il 0..7][d 0..15] floats, 16 KiB per buffer
    __shared__ float xs[2][4096];

    float acc[4][NB];
#pragma unroll
    for (int m = 0; m < 4; ++m)
#pragma unroll
        for (int b = 0; b < NB; ++b) acc[m][b] = 0.0f;

    const float4* __restrict__ x4 = (const float4*)x;
    const float4* __restrict__ W4 = (const float4*)W;

    // prologue: stage chunk 0 into buffer 0 (coalesced: 32-lane groups hit 512B runs)
#pragma unroll
    for (int k = 0; k < 4; ++k) {
        int v = k * 256 + tid;
        int b = v >> 5, r = v & 31;
        ((float4*)xs[0])[v] = x4[(b * NI + ibase0 + (r >> 2)) * 4 + (r & 3)];
    }

    // per-lane W float4 base: W[j, i, c, d] -> f4 idx (j*NI+i)*128 + c*4 + q
    int wbase = (j * NI + (ibase0 + wave * 2 + ip)) * 128 + cb * 4 + q;
    float4 w0 = W4[wbase];
    float4 w1 = W4[wbase + 32];   // c + 8
    float4 w2 = W4[wbase + 64];   // c + 16
    float4 w3 = W4[wbase + 96];   // c + 24

    __syncthreads();

    for (int ch = 0; ch < 16; ++ch) {
        float4 n0, n1, n2, n3, sv0, sv1, sv2, sv3;
        if (ch < 15) {
            // prefetch next chunk's W (hides HBM latency under this chunk's FMAs)
            int wb = wbase + (ch + 1) * 1024;   // +8 i
            n0 = W4[wb]; n1 = W4[wb + 32]; n2 = W4[wb + 64]; n3 = W4[wb + 96];
            // prefetch next chunk's x slice
            int ib = ibase0 + (ch + 1) * 8;
            { int v = tid;       int b = v >> 5, r = v & 31;
              sv0 = x4[(b * NI + ib + (r >> 2)) * 4 + (r & 3)]; }
            { int v = 256 + tid; int b = v >> 5, r = v & 31;
              sv1 = x4[(b * NI + ib + (r >> 2)) * 4 + (r & 3)]; }
            { int v = 512 + tid; int b = v >> 5, r = v & 31;
              sv2 = x4[(b * NI + ib + (r >> 2)) * 4 + (r & 3)]; }
            { int v = 768 + tid; int b = v >> 5, r = v & 31;
              sv3 = x4[(b * NI + ib + (r >> 2)) * 4 + (r & 3)]; }
        }

        const float* xp = xs[ch & 1] + (wave * 2 + ip) * 16 + q * 4;
#pragma unroll
        for (int b = 0; b < NB; ++b) {
            float4 xv = *(const float4*)(xp + b * 128);
            acc[0][b] = fmaf(w0.x, xv.x, acc[0][b]);
            acc[0][b] = fmaf(w0.y, xv.y, acc[0][b]);
            acc[0][b] = fmaf(w0.z, xv.z, acc[0][b]);
            acc[0][b] = fmaf(w0.w, xv.w, acc[0][b]);
            acc[1][b] = fmaf(w1.x, xv.x, acc[1][b]);
            acc[1][b] = fmaf(w1.y, xv.y, acc[1][b]);
            acc[1][b] = fmaf(w1.z, xv.z, acc[1][b]);
            acc[1][b] = fmaf(w1.w, xv.w, acc[1][b]);
            acc[2][b] = fmaf(w2.x, xv.x, acc[2][b]);
            acc[2][b] = fmaf(w2.y, xv.y, acc[2][b]);
            acc[2][b] = fmaf(w2.z, xv.z, acc[2][b]);
            acc[2][b] = fmaf(w2.w, xv.w, acc[2][b]);
            acc[3][b] = fmaf(w3.x, xv.x, acc[3][b]);
            acc[3][b] = fmaf(w3.y, xv.y, acc[3][b]);
            acc[3][b] = fmaf(w3.z, xv.z, acc[3][b]);
            acc[3][b] = fmaf(w3.w, xv.w, acc[3][b]);
        }

        if (ch < 15) {
            float4* dst = (float4*)xs[(ch + 1) & 1];
            dst[tid]       = sv0;
            dst[256 + tid] = sv1;
            dst[512 + tid] = sv2;
            dst[768 + tid] = sv3;
            w0 = n0; w1 = n1; w2 = n2; w3 = n3;
        }
        __syncthreads();
    }

    // reduce over q (lane bits 0,1) and i-parity (bit 5)
#pragma unroll
    for (int m = 0; m < 4; ++m)
#pragma unroll
        for (int b = 0; b < NB; ++b) {
            float v = acc[m][b];
            v += __shfl_xor(v, 1, 64);
            v += __shfl_xor(v, 2, 64);
            v += __shfl_xor(v, 32, 64);
            acc[m][b] = v;
        }

    // cross-wave reduce in LDS (reuse xs), then one atomicAdd per (b,c)
    float* red = (float*)xs;   // need 4*1024 floats, have 8192
    if ((lane & 35) == 0) {    // q==0 && ip==0: 8 lanes, each owns c = cb+8m for all b
#pragma unroll
        for (int m = 0; m < 4; ++m) {
            int c = cb + 8 * m;
#pragma unroll
            for (int b = 0; b < NB; ++b)
                red[(wave * NB + b) * NC + c] = acc[m][b];
        }
    }
    __syncthreads();
#pragma unroll
    for (int r = 0; r < 4; ++r) {
        int oi = r * 256 + tid;          // b*32 + c
        int b = oi >> 5, c = oi & 31;
        float vsum = red[oi] + red[1024 + oi] + red[2048 + oi] + red[3072 + oi];
        atomicAdd(&ws[(b * NJ + j) * NC + c], vsum);
    }
}

// ---------------- finalize: scale by 1/64 and squash over c ----------------
__global__ void caps_finalize(const float* ws, float* out) {
    int o = blockIdx.x * 256 + threadIdx.x;   // (b*64 + j)*32 + c ; grid 256
    float v = ws[o] * (1.0f / 64.0f);
    float sq = v * v;
    sq += __shfl_xor(sq, 1, 64);
    sq += __shfl_xor(sq, 2, 64);
    sq += __shfl_xor(sq, 4, 64);
    sq += __shfl_xor(sq, 8, 64);
    sq += __shfl_xor(sq, 16, 64);   // 32-lane c-group stays within wave half
    float scale = sq / (1.0f + sq) / sqrtf(sq + 1e-7f);
    out[o] = scale * v;
}

extern "C" void kernel_launch(void* const* d_in, const int* in_sizes, int n_in,
                              void* d_out, int out_size, void* d_ws, size_t ws_size,
                              hipStream_t stream) {
    const float* x = (const float*)d_in[0];   // (32, 2048, 16) fp32
    const float* W = (const float*)d_in[1];   // (64, 2048, 32, 16) fp32
    float* out = (float*)d_out;               // (32, 64, 32) fp32

    // accumulator: prefer workspace; fall back to in-place on d_out (finalize is
    // element-local per (b,j)-group, so in-place transform is safe)
    float* acc_buf = (ws_size >= (size_t)65536 * sizeof(float)) ? (float*)d_ws
                                                                : out;

    hipLaunchKernelGGL(caps_init,     dim3(256),  dim3(256), 0, stream, acc_buf);
    hipLaunchKernelGGL(caps_main,     dim3(1024), dim3(256), 0, stream, x, W, acc_buf);
    hipLaunchKernelGGL(caps_finalize, dim3(256),  dim3(256), 0, stream, acc_buf, out);
}